// Round 13
// baseline (409.326 us; speedup 1.0000x reference)
//
#include <hip/hip_runtime.h>
#include <hip/hip_cooperative_groups.h>

namespace cg = cooperative_groups;

// ---------------------------------------------------------------------------
// MatchNet: 3-layer MLP (relu after every layer) -> batched PDHG LP solve.
// Shapes: X[2048,64], W1[64,1024], W2[1024,1024], W3[1024,512], S[64,512].
// Output: x [2048,512] fp32.
//
// R28: cooperative-launch fusion of {prep, gemm1, gemm2, gemm3} into ONE
// kernel (512 blocks x 256 thr = exact 2-blocks/CU capacity, HW grid sync
// via hipLaunchCooperativeKernel -- the guide-blessed safe form of what
// R21's hand spin-barrier attempted and deadlocked). Each phase is R19's
// code verbatim (prep jobs re-chunked to 512 blocks; gemm1 grid was already
// 512; gemm3 on blocks<256). pdhg = separate launch, byte-identical R16
// (92us stable fingerprint). Hypothesis under test: ~58us of the 113us
// non-pdhg time is launch gaps/ramp across 4 dispatch boundaries.
//   pass+faster -> gaps confirmed; pass+same -> gaps disproven, R19 final.
// ---------------------------------------------------------------------------

typedef _Float16 half8 __attribute__((ext_vector_type(8)));
typedef __fp16 fp16x2 __attribute__((ext_vector_type(2)));
typedef __fp16 fp16x4 __attribute__((ext_vector_type(4)));
typedef float floatx4 __attribute__((ext_vector_type(4)));

#define BATCH 2048
#define NITERS 60
#define XBS 520   // delta-xbar LDS row stride in halves
#define YLS 72    // delta-ylo  LDS row stride in halves

typedef const __attribute__((address_space(1))) unsigned int* gptr_as1;
typedef __attribute__((address_space(3))) unsigned int* lptr_as3;
__device__ __forceinline__ void gl_lds16(const _Float16* g, _Float16* s) {
    __builtin_amdgcn_global_load_lds((gptr_as1)g, (lptr_as3)s, 16, 0, 0);
}

// ---- cross-lane sums: DPP (VALU pipe) within 16-lane rows ----
template <int CTRL>
__device__ __forceinline__ float dpp_addf(float x) {
    int y = __builtin_amdgcn_update_dpp(0, __builtin_bit_cast(int, x), CTRL, 0xf, 0xf, true);
    return x + __builtin_bit_cast(float, y);
}
__device__ __forceinline__ float sum16(float x) {
    x = dpp_addf<0xB1>(x);    // quad_perm(1,0,3,2): xor 1
    x = dpp_addf<0x4E>(x);    // quad_perm(2,3,0,1): xor 2
    x = dpp_addf<0x124>(x);   // row_ror:4
    x = dpp_addf<0x128>(x);   // row_ror:8 -> full 16-lane sum in all lanes
    return x;
}
__device__ __forceinline__ float sum64(float x) {
    x = sum16(x);
    x += __builtin_bit_cast(float, __builtin_amdgcn_ds_swizzle(__builtin_bit_cast(int, x), 0x401F)); // xor16
    x += __shfl_xor(x, 32, 64);   // cross-half combine
    return x;
}

// ---------------- 64-dim power iteration for tau (one 256-thread block) --------
// Exact reduction of the reference 512-dim recursion: w_k = S v_k;
//   n_k = sqrt(w'Gw + 2|w|^2 + 1);  w_{k+1} = (Gw + w)/n_k;
//   w_0[i] = rowcount_i / sqrt(512);  L = sqrt(|w_30|^2 + 1);  tau = 0.9/L.
// Shared memory carved from caller smem (fused kernel unions phases).
__device__ void power_64s(const float* __restrict__ S, float* __restrict__ tau_g,
                          char* smem) {
    typedef unsigned long long ull;
    ull (*rowm)[8] = (ull(*)[8])smem;                         // 4096 B
    float (*G)[65] = (float(*)[65])(smem + 4096);             // 16640 B
    float* wl = (float*)(smem + 4096 + 16640);                // 256 B
    float (*pg)[64] = (float(*)[64])(smem + 4096 + 16640 + 256); // 1024 B
    int t = threadIdx.x, wv = t >> 6, ln = t & 63;
    for (int rr = 0; rr < 16; rr++) {
        int r = wv * 16 + rr;
        float v[8];
#pragma unroll
        for (int e = 0; e < 8; e++) v[e] = S[r * 512 + e * 64 + ln];
#pragma unroll
        for (int e = 0; e < 8; e++) {
            unsigned long long m = __ballot(v[e] != 0.f);
            if (ln == 0) rowm[r][e] = m;
        }
    }
    __syncthreads();
    for (int k = 0; k < 16; k++) {
        int idx = t * 16 + k;
        int i = idx >> 6, j = idx & 63;
        int cnt = 0;
#pragma unroll
        for (int e = 0; e < 8; e++) cnt += __popcll(rowm[i][e] & rowm[j][e]);
        G[i][j] = (float)cnt;
    }
    if (wv == 0) {   // w0 = S v0 = rowcount/sqrt(512)
        int cnt = 0;
#pragma unroll
        for (int e = 0; e < 8; e++) cnt += __popcll(rowm[ln][e]);
        wl[ln] = (float)cnt * 0.044194173824159216f;
    }
    __syncthreads();
    for (int s = 0; s < 30; s++) {
        float a = 0.f;
#pragma unroll
        for (int jj = 0; jj < 16; jj++) {
            int j = wv * 16 + jj;
            a += G[ln][j] * wl[j];
        }
        pg[wv][ln] = a;
        __syncthreads();
        if (wv == 0) {
            float g = (pg[0][ln] + pg[1][ln]) + (pg[2][ln] + pg[3][ln]);  // (Gw)[ln]
            float wi = wl[ln];
            float s1 = sum64(wi * g);    // w'Gw
            float s2 = sum64(wi * wi);   // |w|^2
            float n = sqrtf(s1 + 2.f * s2 + 1.f);
            wl[ln] = (g + wi) / n;
        }
        __syncthreads();
    }
    if (wv == 0) {
        float wi = wl[ln];
        float s2 = sum64(wi * wi);
        if (ln == 0) tau_g[0] = 0.9f / sqrtf(s2 + 1.f);
    }
}

// ---------------- 32x32 transpose+cast job: Wt[N][K] <- W[K][N] (R19) ----------
__device__ __forceinline__ void transpose32(const float* __restrict__ W,
                                            _Float16* __restrict__ Wt,
                                            int K, int N, int b, char* smem) {
    float (*tile)[33] = (float(*)[33])smem;
    int nbx = N / 32;
    int n0 = (b % nbx) * 32, k0 = (b / nbx) * 32;
    int tx = threadIdx.x & 31, ty = threadIdx.x >> 5;
#pragma unroll
    for (int i = 0; i < 4; i++)
        tile[ty + i * 8][tx] = W[(size_t)(k0 + ty + i * 8) * N + n0 + tx];
    __syncthreads();
#pragma unroll
    for (int i = 0; i < 4; i++)
        Wt[(size_t)(n0 + ty + i * 8) * K + k0 + tx] = (_Float16)tile[tx][ty + i * 8];
}

// ---------------- 64x64 GEMM tile (R19 single-buffered body, device fn) --------
// out = relu(A[M,K] @ Wt^T + bias) tile at (bm,bn). XOR-swizzled LDS:
// pre-swizzled global source chunk (linear gl_lds dest, rule #21); read XOR
// ((lm>>1)&7)<<3 halves -> frag ds_read_b128 <=2-way banked.
__device__ void gemm_tile(
    const _Float16* __restrict__ A, const _Float16* __restrict__ Wt,
    const float* __restrict__ bias, _Float16* __restrict__ outh,
    float* __restrict__ outf, int N, int K, int bm, int bn, char* smem) {
    _Float16* As = (_Float16*)smem;              // 64*32 halves (4096 B)
    _Float16* Bs = (_Float16*)(smem + 4096);     // 64*32 halves (4096 B)
    int tid = threadIdx.x;
    int w = tid >> 6, l = tid & 63;
    int wr = w >> 1, wc = w & 1;      // wave output tile: rows wr*32, cols wc*32
    int lm = l & 15, q = l >> 4;
    floatx4 acc[2][2] = {};

    int lc = l ^ ((l >> 3) & 7);      // pre-swizzled global chunk (involution)
    int srow = w * 16 + (lc >> 2), scol = (lc & 3) * 8;
    const _Float16* ag = A + (size_t)(bm + srow) * K + scol;
    const _Float16* bg = Wt + (size_t)(bn + srow) * K + scol;
    _Float16* as = &As[(w * 16) * 32];
    _Float16* bs = &Bs[(w * 16) * 32];
    int sx = ((lm >> 1) & 7) << 3;    // read-side XOR in halves

    for (int k0 = 0; k0 < K; k0 += 32) {
        gl_lds16(ag + k0, as);
        gl_lds16(bg + k0, bs);
        __syncthreads();
        half8 af[2], bf[2];
#pragma unroll
        for (int mt = 0; mt < 2; mt++)
            af[mt] = *(const half8*)&As[((wr * 32 + mt * 16 + lm) * 32 + q * 8) ^ sx];
#pragma unroll
        for (int nt = 0; nt < 2; nt++)
            bf[nt] = *(const half8*)&Bs[((wc * 32 + nt * 16 + lm) * 32 + q * 8) ^ sx];
#pragma unroll
        for (int mt = 0; mt < 2; mt++)
#pragma unroll
            for (int nt = 0; nt < 2; nt++)
                acc[mt][nt] = __builtin_amdgcn_mfma_f32_16x16x32_f16(
                    af[mt], bf[nt], acc[mt][nt], 0, 0, 0);
        __syncthreads();
    }
#pragma unroll
    for (int nt = 0; nt < 2; nt++) {
        int col = bn + wc * 32 + nt * 16 + lm;
        float bv = bias[col];
#pragma unroll
        for (int mt = 0; mt < 2; mt++) {
#pragma unroll
            for (int v = 0; v < 4; v++) {
                int row = bm + wr * 32 + mt * 16 + q * 4 + v;
                float val = fmaxf(acc[mt][nt][v] + bv, 0.f);
                if (outh) outh[(size_t)row * N + col] = (_Float16)val;
                else      outf[(size_t)row * N + col] = val;
            }
        }
    }
}

// ---------------- fused cooperative: prep -> gemm1 -> gemm2 -> gemm3 ----------
// 512 blocks x 256 thr = exact 2-blocks/CU capacity; grid.sync between phases.
__global__ __launch_bounds__(256, 2) void fused(
    const float* __restrict__ X, _Float16* __restrict__ Xh,
    const float* __restrict__ W1, _Float16* __restrict__ W1t,
    const float* __restrict__ W2, _Float16* __restrict__ W2t,
    const float* __restrict__ W3, _Float16* __restrict__ W3t,
    const float* __restrict__ S, _Float16* __restrict__ s1f,
    _Float16* __restrict__ s2f, const float* __restrict__ b1,
    _Float16* __restrict__ H1, const float* __restrict__ b2,
    _Float16* __restrict__ H2, const float* __restrict__ b3,
    float* __restrict__ Zb, float* __restrict__ tau_g) {
    __shared__ __align__(16) char smem[22016];
    cg::grid_group grid = cg::this_grid();
    int tid = threadIdx.x;
    int bid = blockIdx.x;

    // ================= phase 0: prep (R19 jobs re-chunked to 512 blocks) =======
    {   // X cast: one element per thread (512*256 = 131072)
        int i = bid * 256 + tid;
        Xh[i] = (_Float16)X[i];
    }
    // W transposes: 1600 jobs; block b does {b, b+512, b+1024} (+1536+b if b<64)
    auto do_t = [&](int j) {
        const float* W; _Float16* Wt; int K, N, b;
        if (j < 64)        { W = W1; Wt = W1t; K = 64;   N = 1024; b = j; }
        else if (j < 1088) { W = W2; Wt = W2t; K = 1024; N = 1024; b = j - 64; }
        else               { W = W3; Wt = W3t; K = 1024; N = 512;  b = j - 1088; }
        transpose32(W, Wt, K, N, b, smem);
    };
    do_t(bid);
    __syncthreads();
    do_t(bid + 512);
    __syncthreads();
    do_t(bid + 1024);
    if (bid < 64) {
        __syncthreads();
        do_t(bid + 1536);
    }
    // S frags (blocks 0..255, R19 mapping) / power_64 (block 511)
    if (bid < 256) {
        int i = bid * 256 + tid;       // 0 .. 65535
        if (i < 4 * 16 * 64 * 8) {     // s1f: B-frag of S^T, k-axis in pi'-order
            int j = i & 7, lane = (i >> 3) & 63, kk = (i >> 9) & 15, wc = i >> 13;
            int pos = kk * 32 + (lane >> 4) * 8 + j;   // storage k position 0..511
            int pp = pos >> 7, r = pos & 127;
            int hh = r >> 6, r2 = r & 63;
            int lmc = r2 >> 2, t3 = r2 & 3;
            int c = pp * 128 + (hh * 4 + t3) * 16 + lmc;   // pi'^-1
            int m = wc * 16 + (lane & 15);
            s1f[i] = (_Float16)S[m * 512 + c];
        } else {                       // s2f: B-frag of S (k = combos)
            int i2 = i - 4 * 16 * 64 * 8;
            int j = i2 & 7, lane = (i2 >> 3) & 63, c = (i2 >> 9) & 1,
                tt = (i2 >> 10) & 7, wc = i2 >> 13;
            int kc = c * 32 + (lane >> 4) * 8 + j;
            int n = wc * 128 + tt * 16 + (lane & 15);
            s2f[i2] = (_Float16)S[kc * 512 + n];
        }
    } else if (bid == 511) {
        __syncthreads();
        power_64s(S, tau_g, smem);
    }
    grid.sync();

    // ================= phase 1: gemm1 (512 tiles = 32x16, K=64) ================
    gemm_tile(Xh, W1t, b1, H1, (float*)nullptr, 1024, 64,
              (bid >> 4) * 64, (bid & 15) * 64, smem);
    grid.sync();

    // ================= phase 2: gemm2 (512 tiles = 32x16, K=1024) ==============
    gemm_tile(H1, W2t, b2, H2, (float*)nullptr, 1024, 1024,
              (bid >> 4) * 64, (bid & 15) * 64, smem);
    grid.sync();

    // ================= phase 3: gemm3 (256 tiles = 32x8, K=1024) ===============
    if (bid < 256)
        gemm_tile(H2, W3t, b3, (_Float16*)nullptr, Zb, 512, 1024,
                  (bid >> 3) * 64, (bid & 7) * 64, smem);
}

// ---------------- Delta-form MFMA PDHG, 4 waves, 3 barriers (R16 exact) --------
// Wave p owns columns [p*128, p*128+128). Lane l: lm=l&15, q=l>>4.
// Lane owns batch rows (q&1)*4+v (v=0..3) and columns ((q>>1)*4+t)*16+lm.
// LDS tiles have 8 REAL rows; MFMA A-frags read row (lm&7) -> broadcast pairs,
// out rows 8-15 are live duplicates consumed by q>=2 lanes (tt=4..7 groups).
__global__ __launch_bounds__(256, 1) void pdhg_mfma(
    const float* __restrict__ Zb, const float* __restrict__ Xf,
    const _Float16* __restrict__ s1f, const _Float16* __restrict__ s2f,
    const float* __restrict__ tau_p, float* __restrict__ out) {
    __shared__ __align__(16) _Float16 xb_d[8 * XBS];
    __shared__ __align__(16) _Float16 yl_d[8 * YLS];
    __shared__ __align__(16) float red[8][4];
    int tid = threadIdx.x;
    int p = tid >> 6;                 // wave = column slice
    int l = tid & 63, lm = l & 15, q = l >> 4;
    int lq = lm & 7;                  // 8-row read index (broadcast pairs)
    int qa = q & 1;                   // row group: rows qa*4+v
    int h = q >> 1;                   // column half: tt group h*4..h*4+3
    int b0 = blockIdx.x * 8;

    half8 s1[16], s2[8][2];
#pragma unroll
    for (int k = 0; k < 16; k++)
        s1[k] = *(const half8*)&s1f[((p * 16 + k) * 64 + l) * 8];
#pragma unroll
    for (int u = 0; u < 8; u++)
#pragma unroll
        for (int c = 0; c < 2; c++)
            s2[u][c] = *(const half8*)&s2f[(((p * 8 + u) * 2 + c) * 64 + l) * 8];

    floatx4 z4[4], tz4[4], x4[4], xb4[4], yh4[4], d4[4];
    floatx4 ylo = {}, Bc;
    floatx4 a1p[4] = {};
    floatx4 acc2[8] = {};
    const floatx4 zero4 = {0.f, 0.f, 0.f, 0.f};
    float tau = tau_p[0];
    float sig = tau;

#pragma unroll
    for (int v = 0; v < 4; v++)
        Bc[v] = Xf[(b0 + qa * 4 + v) * 64 + p * 16 + lm];
#pragma unroll
    for (int t = 0; t < 4; t++) {
#pragma unroll
        for (int v = 0; v < 4; v++) {
            float zz = Zb[(size_t)(b0 + qa * 4 + v) * 512 + p * 128 + (h * 4 + t) * 16 + lm];
            z4[t][v] = zz;
            tz4[t][v] = tau - zz;
        }
        x4[t] = zero4; xb4[t] = zero4; yh4[t] = zero4;
    }
    {
        half8 hz = {0, 0, 0, 0, 0, 0, 0, 0};
        for (int i = tid; i < (8 * XBS) / 8; i += 256)
            *(half8*)&xb_d[i * 8] = hz;
        for (int i = tid; i < 8 * YLS; i += 256)
            yl_d[i] = (_Float16)0.f;
    }
    __syncthreads();

#pragma unroll 1
    for (int it = 0; it < NITERS; ++it) {
        // ---- Kx (delta accumulated): a1p += dxbar @ S^T, storage in pi'-order
#pragma unroll
        for (int k = 0; k < 16; k++) {
            half8 ad = *(const half8*)&xb_d[lq * XBS + k * 32 + q * 8];
            a1p[k & 3] = __builtin_amdgcn_mfma_f32_16x16x32_f16(ad, s1[k], a1p[k & 3], 0, 0, 0);
        }
        floatx4 a1 = (a1p[0] + a1p[1]) + (a1p[2] + a1p[3]);
        // ---- y_lo update (rows qa*4+v, combo p*16+lm); q>=2 lanes duplicate
        floatx4 yv = __builtin_elementwise_max(ylo + sig * (a1 - Bc), zero4);
        floatx4 dy = yv - ylo;
        ylo = yv;
        if (q < 2) {
#pragma unroll
            for (int v = 0; v < 4; v++)
                yl_d[(q * 4 + v) * YLS + p * 16 + lm] = (_Float16)dy[v];
        }
        __syncthreads();   // [A]
        // ---- KTy (delta accumulated): acc2 += dy @ S
        half8 a2d[2];
#pragma unroll
        for (int c = 0; c < 2; c++)
            a2d[c] = *(const half8*)&yl_d[lq * YLS + c * 32 + q * 8];
#pragma unroll
        for (int u = 0; u < 8; u++)
#pragma unroll
            for (int c = 0; c < 2; c++)
                acc2[u] = __builtin_amdgcn_mfma_f32_16x16x32_f16(a2d[c], s2[u][c], acc2[u], 0, 0, 0);
        // ---- elementwise: all lanes real (h selects tt group)
        floatx4 pn = {};
#pragma unroll
        for (int t = 0; t < 4; t++) {
            floatx4 accs = h ? acc2[t + 4] : acc2[t];
            yh4[t] = __builtin_elementwise_max(yh4[t] - sig * xb4[t], zero4);
            floatx4 kty = accs - yh4[t];
            floatx4 dd = (x4[t] - tau * kty) + tz4[t];
            d4[t] = dd;
            pn += dd * dd;
        }
        // ---- row-norm reduce: 16 lanes (DPP) + q-partner (xor32) + 4 waves (LDS)
#pragma unroll
        for (int v = 0; v < 4; v++) pn[v] = sum16(pn[v]);
#pragma unroll
        for (int v = 0; v < 4; v++) pn[v] += __shfl_xor(pn[v], 32, 64);
        if (lm == 0 && q < 2) {
#pragma unroll
            for (int v = 0; v < 4; v++) red[q * 4 + v][p] = pn[v];
        }
        __syncthreads();   // [B]
        floatx4 sv;
#pragma unroll
        for (int v = 0; v < 4; v++) {
            floatx4 rr = *(const floatx4*)&red[qa * 4 + v][0];
            float n2 = (rr.x + rr.y) + (rr.z + rr.w);
            sv[v] = fmaxf(1.f - tau * rsqrtf(fmaxf(n2, 1e-24f)), 0.f);
        }
#pragma unroll
        for (int t = 0; t < 4; t++) {
            floatx4 xn = z4[t] + sv * d4[t];
            floatx4 xbn = 2.f * xn - x4[t];
            d4[t] = xbn - xb4[t];   // reuse d4 as delta
            x4[t] = xn;
            xb4[t] = xbn;
        }
        // ---- write delta-xbar f16 at pi'(row, p, h, lm, t): contiguous fp16x4
#pragma unroll
        for (int v = 0; v < 4; v++) {
            fp16x2 p0 = __builtin_amdgcn_cvt_pkrtz(d4[0][v], d4[1][v]);
            fp16x2 p1 = __builtin_amdgcn_cvt_pkrtz(d4[2][v], d4[3][v]);
            fp16x4 hd = __builtin_shufflevector(p0, p1, 0, 1, 2, 3);
            *(fp16x4*)&xb_d[(qa * 4 + v) * XBS + p * 128 + h * 64 + lm * 4] = hd;
        }
        __syncthreads();   // [C]
    }
#pragma unroll
    for (int t = 0; t < 4; t++)
#pragma unroll
        for (int v = 0; v < 4; v++)
            out[(size_t)(b0 + qa * 4 + v) * 512 + p * 128 + (h * 4 + t) * 16 + lm] = x4[t][v];
}

// ---------------------------------------------------------------------------
extern "C" void kernel_launch(void* const* d_in, const int* in_sizes, int n_in,
                              void* d_out, int out_size, void* d_ws, size_t ws_size,
                              hipStream_t stream) {
    const float* X  = (const float*)d_in[0];
    const float* W1 = (const float*)d_in[1];
    const float* b1 = (const float*)d_in[2];
    const float* W2 = (const float*)d_in[3];
    const float* b2 = (const float*)d_in[4];
    const float* W3 = (const float*)d_in[5];
    const float* b3 = (const float*)d_in[6];
    const float* S  = (const float*)d_in[7];
    float* out = (float*)d_out;

    char* ws = (char*)d_ws;
    size_t off = 0;
    auto alloc = [&](size_t bytes) {
        void* p = ws + off;
        off += (bytes + 255) & ~(size_t)255;
        return p;
    };
    _Float16* Xh  = (_Float16*)alloc((size_t)BATCH * 64 * 2);
    _Float16* W1t = (_Float16*)alloc((size_t)64 * 1024 * 2);
    _Float16* W2t = (_Float16*)alloc((size_t)1024 * 1024 * 2);
    _Float16* W3t = (_Float16*)alloc((size_t)1024 * 512 * 2);
    _Float16* H1  = (_Float16*)alloc((size_t)BATCH * 1024 * 2);
    _Float16* H2  = (_Float16*)alloc((size_t)BATCH * 1024 * 2);
    float*    Zb  = (float*)alloc((size_t)BATCH * 512 * 4);
    _Float16* s1f = (_Float16*)alloc((size_t)4 * 16 * 64 * 8 * 2);
    _Float16* s2f = (_Float16*)alloc((size_t)4 * 8 * 2 * 64 * 8 * 2);
    float*    tau = (float*)alloc(256);

    void* args[] = {(void*)&X,  (void*)&Xh,  (void*)&W1, (void*)&W1t,
                    (void*)&W2, (void*)&W2t, (void*)&W3, (void*)&W3t,
                    (void*)&S,  (void*)&s1f, (void*)&s2f, (void*)&b1,
                    (void*)&H1, (void*)&b2,  (void*)&H2, (void*)&b3,
                    (void*)&Zb, (void*)&tau};
    hipLaunchCooperativeKernel((void*)fused, dim3(512), dim3(256),
                               args, 0, stream);
    hipLaunchKernelGGL(pdhg_mfma, dim3(BATCH / 8), dim3(256), 0, stream,
                       Zb, X, s1f, s2f, tau, out);
}

// Round 14
// 204.231 us; speedup vs baseline: 2.0042x; 2.0042x over previous
//
#include <hip/hip_runtime.h>

// ---------------------------------------------------------------------------
// MatchNet: 3-layer MLP (relu after every layer) -> batched PDHG LP solve.
// Shapes: X[2048,64], W1[64,1024], W2[1024,1024], W3[1024,512], S[64,512].
// Output: x [2048,512] fp32.
//
// R29 (FINAL): R19 verbatim — the session optimum, reproduced twice
// (203.9 / 206.0 us). Structure: prep (casts/transposes/S-frags) ->
// 3x tiled 64x64 gemm_relu (2 blocks/CU, XOR-swizzled LDS, power_64
// piggybacked on gemm2's spare column) -> R16 delta-form PDHG (92us,
// 4-wave/3-barrier chain-latency local optimum).
//
// Exhausted alternatives (all measured worse): R17 2x-occupancy pdhg (107),
// R18 2-barrier pdhg (120), R20 head-merge+db (213), R21 spin-barrier
// (deadlock), R22 db-gemms (216), R23 row-local mega (280), R24/25
// frag-packed mega (233), R26 8-wave split mlp (248), R28 cooperative
// grid.sync fusion (409; grid.sync ~50-70us/sync on 8-XCD gfx950).
// Launch-gap hypothesis disproven; pdhg chain-bound; pipeline stages too
// small to fill 256 CUs — structural floor for this decomposition.
// ---------------------------------------------------------------------------

typedef _Float16 half8 __attribute__((ext_vector_type(8)));
typedef __fp16 fp16x2 __attribute__((ext_vector_type(2)));
typedef __fp16 fp16x4 __attribute__((ext_vector_type(4)));
typedef float floatx4 __attribute__((ext_vector_type(4)));
typedef float floatx2 __attribute__((ext_vector_type(2)));

#define BATCH 2048
#define NITERS 60
#define XBS 520   // delta-xbar LDS row stride in halves
#define YLS 72    // delta-ylo  LDS row stride in halves

typedef const __attribute__((address_space(1))) unsigned int* gptr_as1;
typedef __attribute__((address_space(3))) unsigned int* lptr_as3;
__device__ __forceinline__ void gl_lds16(const _Float16* g, _Float16* s) {
    __builtin_amdgcn_global_load_lds((gptr_as1)g, (lptr_as3)s, 16, 0, 0);
}

// ---- cross-lane sums: DPP (VALU pipe) within 16-lane rows ----
template <int CTRL>
__device__ __forceinline__ float dpp_addf(float x) {
    int y = __builtin_amdgcn_update_dpp(0, __builtin_bit_cast(int, x), CTRL, 0xf, 0xf, true);
    return x + __builtin_bit_cast(float, y);
}
__device__ __forceinline__ float sum16(float x) {
    x = dpp_addf<0xB1>(x);    // quad_perm(1,0,3,2): xor 1
    x = dpp_addf<0x4E>(x);    // quad_perm(2,3,0,1): xor 2
    x = dpp_addf<0x124>(x);   // row_ror:4
    x = dpp_addf<0x128>(x);   // row_ror:8 -> full 16-lane sum in all lanes
    return x;
}
__device__ __forceinline__ float sum64(float x) {
    x = sum16(x);
    x += __builtin_bit_cast(float, __builtin_amdgcn_ds_swizzle(__builtin_bit_cast(int, x), 0x401F)); // xor16
    x += __shfl_xor(x, 32, 64);   // cross-half combine
    return x;
}

// ---------------- 64-dim power iteration for tau (one 256-thread block) --------
// Exact reduction of the reference 512-dim recursion: w_k = S v_k;
//   n_k = sqrt(w'Gw + 2|w|^2 + 1);  w_{k+1} = (Gw + w)/n_k;
//   w_0[i] = rowcount_i / sqrt(512);  L = sqrt(|w_30|^2 + 1);  tau = 0.9/L.
__device__ void power_64(const float* __restrict__ S, float* __restrict__ tau_g) {
    __shared__ unsigned long long rowm[64][8];   // row bitmasks of S
    __shared__ float G[64][65];                  // Gram, +1 pad (conflict-free)
    __shared__ float wl[64], pg[4][64];
    int t = threadIdx.x, wv = t >> 6, ln = t & 63;
    for (int rr = 0; rr < 16; rr++) {
        int r = wv * 16 + rr;
        float v[8];
#pragma unroll
        for (int e = 0; e < 8; e++) v[e] = S[r * 512 + e * 64 + ln];
#pragma unroll
        for (int e = 0; e < 8; e++) {
            unsigned long long m = __ballot(v[e] != 0.f);
            if (ln == 0) rowm[r][e] = m;
        }
    }
    __syncthreads();
    for (int k = 0; k < 16; k++) {
        int idx = t * 16 + k;
        int i = idx >> 6, j = idx & 63;
        int cnt = 0;
#pragma unroll
        for (int e = 0; e < 8; e++) cnt += __popcll(rowm[i][e] & rowm[j][e]);
        G[i][j] = (float)cnt;
    }
    if (wv == 0) {   // w0 = S v0 = rowcount/sqrt(512)
        int cnt = 0;
#pragma unroll
        for (int e = 0; e < 8; e++) cnt += __popcll(rowm[ln][e]);
        wl[ln] = (float)cnt * 0.044194173824159216f;
    }
    __syncthreads();
    for (int s = 0; s < 30; s++) {
        float a = 0.f;
#pragma unroll
        for (int jj = 0; jj < 16; jj++) {
            int j = wv * 16 + jj;
            a += G[ln][j] * wl[j];
        }
        pg[wv][ln] = a;
        __syncthreads();
        if (wv == 0) {
            float g = (pg[0][ln] + pg[1][ln]) + (pg[2][ln] + pg[3][ln]);  // (Gw)[ln]
            float wi = wl[ln];
            float s1 = sum64(wi * g);    // w'Gw
            float s2 = sum64(wi * wi);   // |w|^2
            float n = sqrtf(s1 + 2.f * s2 + 1.f);
            wl[ln] = (g + wi) / n;
        }
        __syncthreads();
    }
    if (wv == 0) {
        float wi = wl[ln];
        float s2 = sum64(wi * wi);
        if (ln == 0) tau_g[0] = 0.9f / sqrtf(s2 + 1.f);
    }
}

// ---------------- merged prep: cast X, W transposes, S frags -------------------
__global__ __launch_bounds__(256) void prep(
    const float* __restrict__ X, _Float16* __restrict__ Xh,
    const float* __restrict__ W1, _Float16* __restrict__ W1t,
    const float* __restrict__ W2, _Float16* __restrict__ W2t,
    const float* __restrict__ W3, _Float16* __restrict__ W3t,
    const float* __restrict__ S, _Float16* __restrict__ s1f,
    _Float16* __restrict__ s2f) {
    __shared__ float tile[32][33];
    int tid = threadIdx.x;
    int bid = blockIdx.x;
    if (bid < 512) {
        int i = bid * 256 + tid;
        Xh[i] = (_Float16)X[i];
        return;
    }
    bid -= 512;
    if (bid < 1600) {   // transpose+cast W[K][N] -> Wt[N][K]
        const float* W; _Float16* Wt; int K, N, b;
        if (bid < 64)        { W = W1; Wt = W1t; K = 64;   N = 1024; b = bid; }
        else if (bid < 1088) { W = W2; Wt = W2t; K = 1024; N = 1024; b = bid - 64; }
        else                 { W = W3; Wt = W3t; K = 1024; N = 512;  b = bid - 1088; }
        int nbx = N / 32;
        int n0 = (b % nbx) * 32, k0 = (b / nbx) * 32;
        int tx = tid & 31, ty = tid >> 5;
#pragma unroll
        for (int i = 0; i < 4; i++)
            tile[ty + i * 8][tx] = W[(size_t)(k0 + ty + i * 8) * N + n0 + tx];
        __syncthreads();
#pragma unroll
        for (int i = 0; i < 4; i++)
            Wt[(size_t)(n0 + ty + i * 8) * K + k0 + tx] = (_Float16)tile[tx][ty + i * 8];
        return;
    }
    bid -= 1600;
    int i = bid * 256 + tid;       // 0 .. 65535
    if (i < 4 * 16 * 64 * 8) {     // s1f: B-frag of S^T, k-axis in pi'-order
        int j = i & 7, lane = (i >> 3) & 63, kk = (i >> 9) & 15, wc = i >> 13;
        int pos = kk * 32 + (lane >> 4) * 8 + j;   // storage k position 0..511
        int pp = pos >> 7, r = pos & 127;
        int hh = r >> 6, r2 = r & 63;
        int lmc = r2 >> 2, t3 = r2 & 3;
        int c = pp * 128 + (hh * 4 + t3) * 16 + lmc;   // pi'^-1
        int m = wc * 16 + (lane & 15);
        s1f[i] = (_Float16)S[m * 512 + c];
    } else {                       // s2f: B-frag of S (k = combos)
        int i2 = i - 4 * 16 * 64 * 8;
        int j = i2 & 7, lane = (i2 >> 3) & 63, c = (i2 >> 9) & 1,
            tt = (i2 >> 10) & 7, wc = i2 >> 13;
        int kc = c * 32 + (lane >> 4) * 8 + j;
        int n = wc * 128 + tt * 16 + (lane & 15);
        s2f[i2] = (_Float16)S[kc * 512 + n];
    }
}

// ---------------- GEMM: out = relu(A[M,K] @ W[K,N] + bias), f16 in, fp32 acc ---
// 64x64 tile, 4 waves, 2 blocks/CU. XOR-swizzled LDS: staging pre-swizzles the
// GLOBAL source chunk (linear gl_lds dest, rule #21); reads XOR by
// ((lm>>1)&7)<<3 halves -> frag ds_read_b128 is <=2-way banked (free).
// Blocks with bn >= N: block (x = N/64, y = 0) runs power_64 when Sp != null.
__global__ __launch_bounds__(256, 2) void gemm_relu(
    const _Float16* __restrict__ A, const _Float16* __restrict__ Wt,
    const float* __restrict__ bias, _Float16* __restrict__ outh,
    float* __restrict__ outf, int N, int K,
    const float* __restrict__ Sp, float* __restrict__ tau_g) {
    __shared__ __align__(16) _Float16 As[64 * 32];
    __shared__ __align__(16) _Float16 Bs[64 * 32];
    int tid = threadIdx.x;
    int bm = blockIdx.y * 64;
    int bn = blockIdx.x * 64;
    if (bn >= N) {
        if (blockIdx.y == 0 && Sp) power_64(Sp, tau_g);
        return;
    }
    int w = tid >> 6, l = tid & 63;
    int wr = w >> 1, wc = w & 1;      // wave output tile: rows wr*32, cols wc*32
    int lm = l & 15, q = l >> 4;
    floatx4 acc[2][2] = {};

    // staging: lane l fills phys chunk l of its wave's 16-row region; the
    // logical chunk there is lc = l ^ ((l>>3)&7)  (involution with read XOR)
    int lc = l ^ ((l >> 3) & 7);
    int srow = w * 16 + (lc >> 2), scol = (lc & 3) * 8;
    const _Float16* ag = A + (size_t)(bm + srow) * K + scol;
    const _Float16* bg = Wt + (size_t)(bn + srow) * K + scol;
    _Float16* as = &As[(w * 16) * 32];
    _Float16* bs = &Bs[(w * 16) * 32];
    int sx = ((lm >> 1) & 7) << 3;    // read-side XOR in halves

    for (int k0 = 0; k0 < K; k0 += 32) {
        gl_lds16(ag + k0, as);
        gl_lds16(bg + k0, bs);
        __syncthreads();
        half8 af[2], bf[2];
#pragma unroll
        for (int mt = 0; mt < 2; mt++)
            af[mt] = *(const half8*)&As[((wr * 32 + mt * 16 + lm) * 32 + q * 8) ^ sx];
#pragma unroll
        for (int nt = 0; nt < 2; nt++)
            bf[nt] = *(const half8*)&Bs[((wc * 32 + nt * 16 + lm) * 32 + q * 8) ^ sx];
#pragma unroll
        for (int mt = 0; mt < 2; mt++)
#pragma unroll
            for (int nt = 0; nt < 2; nt++)
                acc[mt][nt] = __builtin_amdgcn_mfma_f32_16x16x32_f16(
                    af[mt], bf[nt], acc[mt][nt], 0, 0, 0);
        __syncthreads();
    }
#pragma unroll
    for (int nt = 0; nt < 2; nt++) {
        int col = bn + wc * 32 + nt * 16 + lm;
        float bv = bias[col];
#pragma unroll
        for (int mt = 0; mt < 2; mt++) {
#pragma unroll
            for (int v = 0; v < 4; v++) {
                int row = bm + wr * 32 + mt * 16 + q * 4 + v;
                float val = fmaxf(acc[mt][nt][v] + bv, 0.f);
                if (outh) outh[(size_t)row * N + col] = (_Float16)val;
                else      outf[(size_t)row * N + col] = val;
            }
        }
    }
}

// ---------------- Delta-form MFMA PDHG, 4 waves, 3 barriers (R16 exact) --------
// Wave p owns columns [p*128, p*128+128). Lane l: lm=l&15, q=l>>4.
// Lane owns batch rows (q&1)*4+v (v=0..3) and columns ((q>>1)*4+t)*16+lm.
// LDS tiles have 8 REAL rows; MFMA A-frags read row (lm&7) -> broadcast pairs,
// out rows 8-15 are live duplicates consumed by q>=2 lanes (tt=4..7 groups).
__global__ __launch_bounds__(256, 1) void pdhg_mfma(
    const float* __restrict__ Zb, const float* __restrict__ Xf,
    const _Float16* __restrict__ s1f, const _Float16* __restrict__ s2f,
    const float* __restrict__ tau_p, float* __restrict__ out) {
    __shared__ __align__(16) _Float16 xb_d[8 * XBS];
    __shared__ __align__(16) _Float16 yl_d[8 * YLS];
    __shared__ __align__(16) float red[8][4];
    int tid = threadIdx.x;
    int p = tid >> 6;                 // wave = column slice
    int l = tid & 63, lm = l & 15, q = l >> 4;
    int lq = lm & 7;                  // 8-row read index (broadcast pairs)
    int qa = q & 1;                   // row group: rows qa*4+v
    int h = q >> 1;                   // column half: tt group h*4..h*4+3
    int b0 = blockIdx.x * 8;

    half8 s1[16], s2[8][2];
#pragma unroll
    for (int k = 0; k < 16; k++)
        s1[k] = *(const half8*)&s1f[((p * 16 + k) * 64 + l) * 8];
#pragma unroll
    for (int u = 0; u < 8; u++)
#pragma unroll
        for (int c = 0; c < 2; c++)
            s2[u][c] = *(const half8*)&s2f[(((p * 8 + u) * 2 + c) * 64 + l) * 8];

    floatx4 z4[4], tz4[4], x4[4], xb4[4], yh4[4], d4[4];
    floatx4 ylo = {}, Bc;
    floatx4 a1p[4] = {};
    floatx4 acc2[8] = {};
    const floatx4 zero4 = {0.f, 0.f, 0.f, 0.f};
    float tau = tau_p[0];
    float sig = tau;

#pragma unroll
    for (int v = 0; v < 4; v++)
        Bc[v] = Xf[(b0 + qa * 4 + v) * 64 + p * 16 + lm];
#pragma unroll
    for (int t = 0; t < 4; t++) {
#pragma unroll
        for (int v = 0; v < 4; v++) {
            float zz = Zb[(size_t)(b0 + qa * 4 + v) * 512 + p * 128 + (h * 4 + t) * 16 + lm];
            z4[t][v] = zz;
            tz4[t][v] = tau - zz;
        }
        x4[t] = zero4; xb4[t] = zero4; yh4[t] = zero4;
    }
    {
        half8 hz = {0, 0, 0, 0, 0, 0, 0, 0};
        for (int i = tid; i < (8 * XBS) / 8; i += 256)
            *(half8*)&xb_d[i * 8] = hz;
        for (int i = tid; i < 8 * YLS; i += 256)
            yl_d[i] = (_Float16)0.f;
    }
    __syncthreads();

#pragma unroll 1
    for (int it = 0; it < NITERS; ++it) {
        // ---- Kx (delta accumulated): a1p += dxbar @ S^T, storage in pi'-order
#pragma unroll
        for (int k = 0; k < 16; k++) {
            half8 ad = *(const half8*)&xb_d[lq * XBS + k * 32 + q * 8];
            a1p[k & 3] = __builtin_amdgcn_mfma_f32_16x16x32_f16(ad, s1[k], a1p[k & 3], 0, 0, 0);
        }
        floatx4 a1 = (a1p[0] + a1p[1]) + (a1p[2] + a1p[3]);
        // ---- y_lo update (rows qa*4+v, combo p*16+lm); q>=2 lanes duplicate
        floatx4 yv = __builtin_elementwise_max(ylo + sig * (a1 - Bc), zero4);
        floatx4 dy = yv - ylo;
        ylo = yv;
        if (q < 2) {
#pragma unroll
            for (int v = 0; v < 4; v++)
                yl_d[(q * 4 + v) * YLS + p * 16 + lm] = (_Float16)dy[v];
        }
        __syncthreads();   // [A]
        // ---- KTy (delta accumulated): acc2 += dy @ S
        half8 a2d[2];
#pragma unroll
        for (int c = 0; c < 2; c++)
            a2d[c] = *(const half8*)&yl_d[lq * YLS + c * 32 + q * 8];
#pragma unroll
        for (int u = 0; u < 8; u++)
#pragma unroll
            for (int c = 0; c < 2; c++)
                acc2[u] = __builtin_amdgcn_mfma_f32_16x16x32_f16(a2d[c], s2[u][c], acc2[u], 0, 0, 0);
        // ---- elementwise: all lanes real (h selects tt group)
        floatx4 pn = {};
#pragma unroll
        for (int t = 0; t < 4; t++) {
            floatx4 accs = h ? acc2[t + 4] : acc2[t];
            yh4[t] = __builtin_elementwise_max(yh4[t] - sig * xb4[t], zero4);
            floatx4 kty = accs - yh4[t];
            floatx4 dd = (x4[t] - tau * kty) + tz4[t];
            d4[t] = dd;
            pn += dd * dd;
        }
        // ---- row-norm reduce: 16 lanes (DPP) + q-partner (xor32) + 4 waves (LDS)
#pragma unroll
        for (int v = 0; v < 4; v++) pn[v] = sum16(pn[v]);
#pragma unroll
        for (int v = 0; v < 4; v++) pn[v] += __shfl_xor(pn[v], 32, 64);
        if (lm == 0 && q < 2) {
#pragma unroll
            for (int v = 0; v < 4; v++) red[q * 4 + v][p] = pn[v];
        }
        __syncthreads();   // [B]
        floatx4 sv;
#pragma unroll
        for (int v = 0; v < 4; v++) {
            floatx4 rr = *(const floatx4*)&red[qa * 4 + v][0];
            float n2 = (rr.x + rr.y) + (rr.z + rr.w);
            sv[v] = fmaxf(1.f - tau * rsqrtf(fmaxf(n2, 1e-24f)), 0.f);
        }
#pragma unroll
        for (int t = 0; t < 4; t++) {
            floatx4 xn = z4[t] + sv * d4[t];
            floatx4 xbn = 2.f * xn - x4[t];
            d4[t] = xbn - xb4[t];   // reuse d4 as delta
            x4[t] = xn;
            xb4[t] = xbn;
        }
        // ---- write delta-xbar f16 at pi'(row, p, h, lm, t): contiguous fp16x4
#pragma unroll
        for (int v = 0; v < 4; v++) {
            fp16x2 p0 = __builtin_amdgcn_cvt_pkrtz(d4[0][v], d4[1][v]);
            fp16x2 p1 = __builtin_amdgcn_cvt_pkrtz(d4[2][v], d4[3][v]);
            fp16x4 hd = __builtin_shufflevector(p0, p1, 0, 1, 2, 3);
            *(fp16x4*)&xb_d[(qa * 4 + v) * XBS + p * 128 + h * 64 + lm * 4] = hd;
        }
        __syncthreads();   // [C]
    }
#pragma unroll
    for (int t = 0; t < 4; t++)
#pragma unroll
        for (int v = 0; v < 4; v++)
            out[(size_t)(b0 + qa * 4 + v) * 512 + p * 128 + (h * 4 + t) * 16 + lm] = x4[t][v];
}

// ---------------------------------------------------------------------------
extern "C" void kernel_launch(void* const* d_in, const int* in_sizes, int n_in,
                              void* d_out, int out_size, void* d_ws, size_t ws_size,
                              hipStream_t stream) {
    const float* X  = (const float*)d_in[0];
    const float* W1 = (const float*)d_in[1];
    const float* b1 = (const float*)d_in[2];
    const float* W2 = (const float*)d_in[3];
    const float* b2 = (const float*)d_in[4];
    const float* W3 = (const float*)d_in[5];
    const float* b3 = (const float*)d_in[6];
    const float* S  = (const float*)d_in[7];
    float* out = (float*)d_out;

    char* ws = (char*)d_ws;
    size_t off = 0;
    auto alloc = [&](size_t bytes) {
        void* p = ws + off;
        off += (bytes + 255) & ~(size_t)255;
        return p;
    };
    _Float16* Xh  = (_Float16*)alloc((size_t)BATCH * 64 * 2);
    _Float16* W1t = (_Float16*)alloc((size_t)64 * 1024 * 2);
    _Float16* W2t = (_Float16*)alloc((size_t)1024 * 1024 * 2);
    _Float16* W3t = (_Float16*)alloc((size_t)1024 * 512 * 2);
    _Float16* H1  = (_Float16*)alloc((size_t)BATCH * 1024 * 2);
    _Float16* H2  = (_Float16*)alloc((size_t)BATCH * 1024 * 2);
    float*    Zb  = (float*)alloc((size_t)BATCH * 512 * 4);
    _Float16* s1f = (_Float16*)alloc((size_t)4 * 16 * 64 * 8 * 2);
    _Float16* s2f = (_Float16*)alloc((size_t)4 * 8 * 2 * 64 * 8 * 2);
    float*    tau = (float*)alloc(256);

    hipLaunchKernelGGL(prep, dim3(2368), dim3(256), 0, stream,
                       X, Xh, W1, W1t, W2, W2t, W3, W3t, S, s1f, s2f);
    hipLaunchKernelGGL(gemm_relu, dim3(16, 32), dim3(256), 0, stream,
                       Xh, W1t, b1, H1, (float*)nullptr, 1024, 64,
                       (const float*)nullptr, (float*)nullptr);
    hipLaunchKernelGGL(gemm_relu, dim3(17, 32), dim3(256), 0, stream,
                       H1, W2t, b2, H2, (float*)nullptr, 1024, 1024, S, tau);
    hipLaunchKernelGGL(gemm_relu, dim3(8, 32), dim3(256), 0, stream,
                       H2, W3t, b3, (_Float16*)nullptr, Zb, 512, 1024,
                       (const float*)nullptr, (float*)nullptr);
    hipLaunchKernelGGL(pdhg_mfma, dim3(BATCH / 8), dim3(256), 0, stream,
                       Zb, X, s1f, s2f, tau, out);
}